// Round 6
// baseline (197.149 us; speedup 1.0000x reference)
//
#include <hip/hip_runtime.h>

#define HW     3136      // 56*56
#define WIDTH  56
#define C      256
#define CR     64
#define NT     64
#define TT     8
#define PW     64        // padded row width (bf16 y)
#define PH     58        // padded rows
#define YPLANE (PH*PW)   // 3712 shorts per (nt,ch) plane
#define YBYTES ((size_t)NT * CR * YPLANE * 2)   // 30,408,704

#define BN_INV 0.9999950000374997f   // 1/sqrt(1+1e-5)

typedef __attribute__((ext_vector_type(8))) short short8;
typedef __attribute__((ext_vector_type(8))) unsigned short ushort8;
typedef __attribute__((ext_vector_type(4))) float f32x4;
typedef __attribute__((ext_vector_type(2))) float f32x2;

static __device__ __forceinline__ float relu(float v) { return fmaxf(v, 0.0f); }
static __device__ __forceinline__ float bf2f(unsigned short u) {
    return __builtin_bit_cast(float, (unsigned)u << 16);
}
static __device__ __forceinline__ unsigned short f2bf(float f) {
    unsigned u = __builtin_bit_cast(unsigned, f);
    unsigned r = (u + 0x7FFFu + ((u >> 16) & 1u)) >> 16;   // RNE
    return (unsigned short)r;
}
static __device__ __forceinline__ unsigned pack2(float a, float b) {
    return (unsigned)f2bf(a) | ((unsigned)f2bf(b) << 16);
}

// zero the halo cells of all 64 planes of frame nt (rows 0,57; col 0; cols 57..63)
static __device__ __forceinline__ void halo_zero(int nt, int tid,
                                                 unsigned short* __restrict__ y) {
    const int ch = tid >> 2, part = tid & 3;
    unsigned short* pl = y + ((size_t)nt * CR + ch) * YPLANE;
    if (part == 0) {
        ushort8 z = (ushort8)0;
#pragma unroll
        for (int j = 0; j < 8; ++j) *(ushort8*)(pl + j * 8) = z;          // row 0
    } else if (part == 1) {
        ushort8 z = (ushort8)0;
        unsigned short* q = pl + 57 * PW;                                  // row 57
#pragma unroll
        for (int j = 0; j < 8; ++j) *(ushort8*)(q + j * 8) = z;
    } else if (part == 2) {
        for (int r = 1; r <= 28; ++r) {
            unsigned short* q = pl + r * PW + 57;                          // col 57..63 + col0(r+1)
#pragma unroll
            for (int j = 0; j < 8; ++j) q[j] = 0;
        }
    } else {
        for (int r = 29; r <= 56; ++r) {
            unsigned short* q = pl + r * PW + 57;
#pragma unroll
            for (int j = 0; j < 8; ++j) q[j] = 0;
        }
        pl[PW] = 0;                                                        // row 1 col 0
    }
}

// k1: blocks 0..783: y = relu(bn21(conv21(x))) via MFMA -> bf16 padded layout.
//     blocks 784..847: halo-zero (overlapped).
__global__ __launch_bounds__(256, 2) void k1_mfma(const float* __restrict__ x,
                                                  const float* __restrict__ w21,
                                                  const float* __restrict__ g,
                                                  const float* __restrict__ bb,
                                                  unsigned short* __restrict__ y) {
    const int blk = blockIdx.x;
    const int tid = threadIdx.x;
    if (blk >= 784) { halo_zero(blk - 784, tid, y); return; }

    __shared__ unsigned short Alds[64][264];     // 64 o x (256 c + 8 pad) = 33 KB
    __shared__ unsigned short Blds[4][64][40];   // per-wave 64 px x (32 c + 8 pad) = 20 KB

    const int lane = tid & 63;
    const int wv   = tid >> 6;
    const int gq   = blk / 49;
    const int s    = blk - gq * 49;
    const int p0   = s * 64;
    const int nt   = __builtin_amdgcn_readfirstlane(gq * 4 + wv);

    {   // stage A: convert fp32 weights in-block (w is L2/L3-hot across blocks)
        const int o  = tid >> 2;
        const int cb = (tid & 3) * 64;
        const float* wp = w21 + o * C + cb;
        unsigned short* ap = &Alds[o][cb];
#pragma unroll
        for (int j = 0; j < 8; ++j) {
            f32x4 lo = *(const f32x4*)(wp + j * 8);
            f32x4 hi = *(const f32x4*)(wp + j * 8 + 4);
            union { unsigned d[4]; short8 v; } pk;
            pk.d[0] = pack2(lo.x, lo.y); pk.d[1] = pack2(lo.z, lo.w);
            pk.d[2] = pack2(hi.x, hi.y); pk.d[3] = pack2(hi.z, hi.w);
            *(short8*)(ap + j * 8) = pk.v;
        }
    }
    __syncthreads();   // the only barrier

    const float* xw = x + (size_t)nt * (C * HW) + p0 + lane;
    unsigned short (*Bw)[40] = Blds[wv];

    f32x4 acc[4][4];
#pragma unroll
    for (int nb = 0; nb < 4; ++nb)
#pragma unroll
        for (int mb = 0; mb < 4; ++mb) acc[nb][mb] = (f32x4)0.0f;

    const int frow = lane & 15;
    const int fk8  = (lane >> 4) * 8;

    float buf[2][32];
#pragma unroll
    for (int j = 0; j < 32; ++j) buf[0][j] = xw[(size_t)j * HW];

#pragma unroll
    for (int ks = 0; ks < 8; ++ks) {
        const int cur = ks & 1;
        if (ks < 7) {
            const float* xn = xw + (size_t)((ks + 1) * 32) * HW;
#pragma unroll
            for (int j = 0; j < 32; ++j) buf[cur ^ 1][j] = xn[(size_t)j * HW];
        }
#pragma unroll
        for (int q = 0; q < 4; ++q) {
            union { unsigned d[4]; short8 v; } pk;
#pragma unroll
            for (int jj = 0; jj < 4; ++jj)
                pk.d[jj] = pack2(buf[cur][q * 8 + 2 * jj], buf[cur][q * 8 + 2 * jj + 1]);
            *(short8*)&Bw[lane][q * 8] = pk.v;
        }
        short8 bfrag[4], afrag[4];
#pragma unroll
        for (int nb = 0; nb < 4; ++nb)
            bfrag[nb] = *(const short8*)&Bw[nb * 16 + frow][fk8];
#pragma unroll
        for (int mb = 0; mb < 4; ++mb)
            afrag[mb] = *(const short8*)&Alds[mb * 16 + frow][ks * 32 + fk8];
#pragma unroll
        for (int nb = 0; nb < 4; ++nb)
#pragma unroll
            for (int mb = 0; mb < 4; ++mb)
                acc[nb][mb] = __builtin_amdgcn_mfma_f32_16x16x32_bf16(
                    afrag[mb], bfrag[nb], acc[nb][mb], 0, 0, 0);
    }

    // epilogue: D col = lane&15 (pixel), row = (lane>>4)*4 + r (output o); bf16 store
    unsigned short* ybase = y + (size_t)nt * CR * YPLANE;
    const int rbase = (lane >> 4) * 4;
#pragma unroll
    for (int nb = 0; nb < 4; ++nb) {
        const int p = p0 + nb * 16 + frow;
        const int r = p / WIDTH;
        const int c = p - r * WIDTH;
        const int pidx = (r + 1) * PW + (c + 1);
#pragma unroll
        for (int mb = 0; mb < 4; ++mb)
#pragma unroll
            for (int rr = 0; rr < 4; ++rr) {
                int o = mb * 16 + rbase + rr;
                float v = relu(fmaf(acc[nb][mb][rr], g[o] * BN_INV, bb[o]));
                ybase[(size_t)o * YPLANE + pidx] = f2bf(v);
            }
    }
}

// k2f: fused corr + bn22 + relu + conv22 + bn23 + residual + relu.
// thread = (task, h); task = (nt, row, 8-col group), h = ch-octet & o-quarter(32).
__global__ __launch_bounds__(256, 3) void k2_fused(const unsigned short* __restrict__ y,
                                                   const float* __restrict__ g22,
                                                   const float* __restrict__ b22,
                                                   const float* __restrict__ w2,
                                                   const float* __restrict__ g23,
                                                   const float* __restrict__ b23,
                                                   const float* __restrict__ x,
                                                   float* __restrict__ out) {
    __shared__ float w2s[9][256];   // w2[o][k] * g23[o]*BN_INV, transposed
    __shared__ float b23s[256];
    {
        const int o = threadIdx.x;
        const float sc = g23[o] * BN_INV;
#pragma unroll
        for (int k = 0; k < 9; ++k) w2s[k][o] = w2[o * 9 + k] * sc;
        b23s[o] = b23[o];
    }
    __syncthreads();

    const int gt   = blockIdx.x * 256 + threadIdx.x;   // 0..200703
    const int h    = gt & 7;
    const int task = gt >> 3;                          // 0..25087
    const int nt   = task / 392;
    const int rm   = task - nt * 392;
    const int r    = rm / 7;
    const int cg   = rm - r * 7;
    const int c0   = cg * 8;
    const int nt2  = ((nt & (TT - 1)) < TT - 1) ? nt + 1 : nt;

    const unsigned short* y1 = y + ((size_t)nt * CR + h * 8) * YPLANE
                                 + (size_t)(r + 1) * PW + c0;
    const unsigned short* y2 = y + ((size_t)nt2 * CR + h * 8) * YPLANE
                                 + (size_t)r * PW + c0;

    float acc[9][8];
#pragma unroll
    for (int k = 0; k < 9; ++k)
#pragma unroll
        for (int px = 0; px < 8; ++px) acc[k][px] = 0.0f;

#pragma unroll
    for (int ch = 0; ch < 8; ++ch) {
        const unsigned short* p1 = y1 + (size_t)ch * YPLANE;
        ushort8 a8 = *(const ushort8*)p1;
        unsigned at = *(const unsigned*)(p1 + 8);
        float a[8];
#pragma unroll
        for (int j = 0; j < 7; ++j) a[j] = bf2f(a8[j + 1]);
        a[7] = bf2f((unsigned short)(at & 0xffffu));

        const unsigned short* p2 = y2 + (size_t)ch * YPLANE;
#pragma unroll
        for (int dy = 0; dy < 3; ++dy) {
            const unsigned short* pr = p2 + dy * PW;
            ushort8 b8 = *(const ushort8*)pr;
            unsigned bt = *(const unsigned*)(pr + 8);
            float w[10];
#pragma unroll
            for (int j = 0; j < 8; ++j) w[j] = bf2f(b8[j]);
            w[8] = bf2f((unsigned short)(bt & 0xffffu));
            w[9] = bf2f((unsigned short)(bt >> 16));
#pragma unroll
            for (int dx = 0; dx < 3; ++dx) {
                int k = dy * 3 + dx;
#pragma unroll
                for (int px = 0; px < 8; ++px)
                    acc[k][px] = fmaf(a[px], w[px + dx], acc[k][px]);
            }
        }
    }

    // reduce over the 8 ch-octet lanes; all lanes end with the full sum
#pragma unroll
    for (int k = 0; k < 9; ++k)
#pragma unroll
        for (int px = 0; px < 8; ++px) {
            float v = acc[k][px];
            v += __shfl_xor(v, 1);
            v += __shfl_xor(v, 2);
            v += __shfl_xor(v, 4);
            acc[k][px] = v;
        }

    // bn22 + relu in-register  (scale includes the 1/CR)
#pragma unroll
    for (int k = 0; k < 9; ++k) {
        float sck = g22[k] * (BN_INV / (float)CR);
        float bvk = b22[k];
#pragma unroll
        for (int px = 0; px < 8; ++px)
            acc[k][px] = relu(fmaf(acc[k][px], sck, bvk));
    }

    // conv22 quarter: this lane handles o = h*32 .. h*32+31 for its 8 pixels
    const int pxl = rm * 8;
    const float* xb = x   + (size_t)nt * (C * HW) + pxl;
    float*       ob = out + (size_t)nt * (C * HW) + pxl;

#pragma unroll 2
    for (int oi = 0; oi < 32; ++oi) {
        const int o = h * 32 + oi;
        float wk[9];
#pragma unroll
        for (int k = 0; k < 9; ++k) wk[k] = w2s[k][o];
        const float bv = b23s[o];
        f32x4 xlo = *(const f32x4*)(xb + (size_t)o * HW);
        f32x4 xhi = *(const f32x4*)(xb + (size_t)o * HW + 4);
        float sv[8];
#pragma unroll
        for (int px = 0; px < 8; ++px) {
            float sx = 0.0f;
#pragma unroll
            for (int k = 0; k < 9; ++k) sx = fmaf(wk[k], acc[k][px], sx);
            sv[px] = sx + bv;
        }
        f32x4 olo, ohi;
        olo.x = relu(sv[0] + xlo.x); olo.y = relu(sv[1] + xlo.y);
        olo.z = relu(sv[2] + xlo.z); olo.w = relu(sv[3] + xlo.w);
        ohi.x = relu(sv[4] + xhi.x); ohi.y = relu(sv[5] + xhi.y);
        ohi.z = relu(sv[6] + xhi.z); ohi.w = relu(sv[7] + xhi.w);
        *(f32x4*)(ob + (size_t)o * HW)     = olo;
        *(f32x4*)(ob + (size_t)o * HW + 4) = ohi;
    }
}

// ---------- fallback path (ws too small): round-5 proven kernels ----------
__global__ __launch_bounds__(256) void k2_corr(const unsigned short* __restrict__ y,
                                               const float* __restrict__ g,
                                               const float* __restrict__ bb,
                                               float* __restrict__ cv) {
    int gt   = blockIdx.x * 256 + threadIdx.x;
    int h    = gt & 3;
    int task = gt >> 2;
    int nt   = task / 392;
    int rm   = task - nt * 392;
    int r    = rm / 7;
    int cg   = rm - r * 7;
    int c0   = cg * 8;
    int nt2  = ((nt & (TT - 1)) < TT - 1) ? nt + 1 : nt;

    const unsigned short* y1 = y + ((size_t)nt * CR + h * 16) * YPLANE
                                 + (size_t)(r + 1) * PW + c0;
    const unsigned short* y2 = y + ((size_t)nt2 * CR + h * 16) * YPLANE
                                 + (size_t)r * PW + c0;

    float acc[9][8];
#pragma unroll
    for (int k = 0; k < 9; ++k)
#pragma unroll
        for (int px = 0; px < 8; ++px) acc[k][px] = 0.0f;

#pragma unroll 2
    for (int ch = 0; ch < 16; ++ch) {
        const unsigned short* p1 = y1 + (size_t)ch * YPLANE;
        ushort8 a8 = *(const ushort8*)p1;
        unsigned at = *(const unsigned*)(p1 + 8);
        float a[8];
#pragma unroll
        for (int j = 0; j < 7; ++j) a[j] = bf2f(a8[j + 1]);
        a[7] = bf2f((unsigned short)(at & 0xffffu));
        const unsigned short* p2 = y2 + (size_t)ch * YPLANE;
#pragma unroll
        for (int dy = 0; dy < 3; ++dy) {
            const unsigned short* pr = p2 + dy * PW;
            ushort8 b8 = *(const ushort8*)pr;
            unsigned bt = *(const unsigned*)(pr + 8);
            float w[10];
#pragma unroll
            for (int j = 0; j < 8; ++j) w[j] = bf2f(b8[j]);
            w[8] = bf2f((unsigned short)(bt & 0xffffu));
            w[9] = bf2f((unsigned short)(bt >> 16));
#pragma unroll
            for (int dx = 0; dx < 3; ++dx) {
                int k = dy * 3 + dx;
#pragma unroll
                for (int px = 0; px < 8; ++px)
                    acc[k][px] = fmaf(a[px], w[px + dx], acc[k][px]);
            }
        }
    }
#pragma unroll
    for (int k = 0; k < 9; ++k)
#pragma unroll
        for (int px = 0; px < 8; ++px) {
            float v = acc[k][px];
            v += __shfl_xor(v, 1);
            v += __shfl_xor(v, 2);
            acc[k][px] = v;
        }
    if (h == 0) {
        float* cp = cv + (size_t)nt * 9 * HW + r * WIDTH + c0;
        const float rcr = 1.0f / CR;
#pragma unroll
        for (int k = 0; k < 9; ++k) {
            float sc = g[k] * BN_INV, bv = bb[k];
            f32x4 lo, hi;
            lo.x = relu(fmaf(acc[k][0] * rcr, sc, bv));
            lo.y = relu(fmaf(acc[k][1] * rcr, sc, bv));
            lo.z = relu(fmaf(acc[k][2] * rcr, sc, bv));
            lo.w = relu(fmaf(acc[k][3] * rcr, sc, bv));
            hi.x = relu(fmaf(acc[k][4] * rcr, sc, bv));
            hi.y = relu(fmaf(acc[k][5] * rcr, sc, bv));
            hi.z = relu(fmaf(acc[k][6] * rcr, sc, bv));
            hi.w = relu(fmaf(acc[k][7] * rcr, sc, bv));
            *(f32x4*)(cp + (size_t)k * HW)     = lo;
            *(f32x4*)(cp + (size_t)k * HW + 4) = hi;
        }
    }
}

__global__ __launch_bounds__(256) void k3_conv22(const float* __restrict__ cv,
                                                 const float* __restrict__ w2,
                                                 const float* __restrict__ g,
                                                 const float* __restrict__ bb,
                                                 const float* __restrict__ x,
                                                 float* __restrict__ out) {
    int gt = blockIdx.x * 256 + threadIdx.x;
    int nt = gt / 1568;
    int p2 = (gt - nt * 1568) * 2;
    const float* cp = cv + (size_t)nt * 9 * HW + p2;
    float cvx[9], cvy[9];
#pragma unroll
    for (int k = 0; k < 9; ++k) {
        f32x2 v = *(const f32x2*)(cp + (size_t)k * HW);
        cvx[k] = v.x; cvy[k] = v.y;
    }
    const float* xp = x   + (size_t)nt * (C * HW) + p2;
    float*       op = out + (size_t)nt * (C * HW) + p2;
#pragma unroll 8
    for (int o = 0; o < C; ++o) {
        const float* wr = w2 + o * 9;
        f32x2 xr = *(const f32x2*)(xp + (size_t)o * HW);
        float sx = 0.0f, sy = 0.0f;
#pragma unroll
        for (int k = 0; k < 9; ++k) {
            float wv = wr[k];
            sx = fmaf(wv, cvx[k], sx);
            sy = fmaf(wv, cvy[k], sy);
        }
        float sc = g[o] * BN_INV, bv = bb[o];
        f32x2 rv;
        rv.x = relu(fmaf(sx, sc, bv) + xr.x);
        rv.y = relu(fmaf(sy, sc, bv) + xr.y);
        *(f32x2*)(op + (size_t)o * HW) = rv;
    }
}

extern "C" void kernel_launch(void* const* d_in, const int* in_sizes, int n_in,
                              void* d_out, int out_size, void* d_ws, size_t ws_size,
                              hipStream_t stream) {
    const float* x   = (const float*)d_in[0];
    const float* w21 = (const float*)d_in[1];
    const float* g21 = (const float*)d_in[2];
    const float* b21 = (const float*)d_in[3];
    const float* g22 = (const float*)d_in[4];
    const float* b22 = (const float*)d_in[5];
    const float* w22 = (const float*)d_in[6];
    const float* g23 = (const float*)d_in[7];
    const float* b23 = (const float*)d_in[8];
    float* out = (float*)d_out;

    if (ws_size >= YBYTES) {
        // fused path: y bf16 padded in d_ws; conv22 fused into corr
        unsigned short* yb = (unsigned short*)d_ws;
        k1_mfma <<<848, 256, 0, stream>>>(x, w21, g21, b21, yb);
        k2_fused<<<784, 256, 0, stream>>>(yb, g22, b22, w22, g23, b23, x, out);
    } else {
        // fallback: y in d_out (dead before k3 overwrites), cv in ws
        unsigned short* yb = (unsigned short*)d_out;
        float* cvb = (float*)d_ws;
        k1_mfma  <<<848, 256, 0, stream>>>(x, w21, g21, b21, yb);
        k2_corr  <<<392, 256, 0, stream>>>(yb, g22, b22, cvb);
        k3_conv22<<<392, 256, 0, stream>>>(cvb, w22, g23, b23, x, out);
    }
}

// Round 7
// 176.719 us; speedup vs baseline: 1.1156x; 1.1156x over previous
//
#include <hip/hip_runtime.h>

#define HW     3136      // 56*56
#define WIDTH  56
#define C      256
#define CR     64
#define NT     64
#define TT     8
#define PW     64        // padded row width (bf16 y)
#define PH     58        // padded rows
#define YPLANE (PH*PW)   // 3712 shorts per (nt,ch) plane
#define YBYTES ((size_t)NT * CR * YPLANE * 2)   // 30,408,704

#define BN_INV 0.9999950000374997f   // 1/sqrt(1+1e-5)

typedef __attribute__((ext_vector_type(8))) short short8;
typedef __attribute__((ext_vector_type(8))) unsigned short ushort8;
typedef __attribute__((ext_vector_type(4))) float f32x4;
typedef __attribute__((ext_vector_type(2))) float f32x2;

static __device__ __forceinline__ float relu(float v) { return fmaxf(v, 0.0f); }
static __device__ __forceinline__ float bfLO(unsigned u) {          // low bf16 of dword
    return __builtin_bit_cast(float, u << 16);
}
static __device__ __forceinline__ float bfHI(unsigned u) {          // high bf16 of dword
    return __builtin_bit_cast(float, u & 0xFFFF0000u);
}
static __device__ __forceinline__ unsigned short f2bf(float f) {
    unsigned u = __builtin_bit_cast(unsigned, f);
    unsigned r = (u + 0x7FFFu + ((u >> 16) & 1u)) >> 16;   // RNE
    return (unsigned short)r;
}
static __device__ __forceinline__ unsigned pack2(float a, float b) {
    return (unsigned)f2bf(a) | ((unsigned)f2bf(b) << 16);
}

// zero the halo cells of all 64 planes of frame nt (rows 0,57; col 0; cols 57..63)
static __device__ __forceinline__ void halo_zero(int nt, int tid,
                                                 unsigned short* __restrict__ y) {
    const int ch = tid >> 2, part = tid & 3;
    unsigned short* pl = y + ((size_t)nt * CR + ch) * YPLANE;
    if (part == 0) {
        ushort8 z = (ushort8)0;
#pragma unroll
        for (int j = 0; j < 8; ++j) *(ushort8*)(pl + j * 8) = z;          // row 0
    } else if (part == 1) {
        ushort8 z = (ushort8)0;
        unsigned short* q = pl + 57 * PW;                                  // row 57
#pragma unroll
        for (int j = 0; j < 8; ++j) *(ushort8*)(q + j * 8) = z;
    } else if (part == 2) {
        for (int r = 1; r <= 28; ++r) {
            unsigned short* q = pl + r * PW + 57;
#pragma unroll
            for (int j = 0; j < 8; ++j) q[j] = 0;
        }
    } else {
        for (int r = 29; r <= 56; ++r) {
            unsigned short* q = pl + r * PW + 57;
#pragma unroll
            for (int j = 0; j < 8; ++j) q[j] = 0;
        }
        pl[PW] = 0;                                                        // row 1 col 0
    }
}

// k1: blocks 0..783: y = relu(bn21(conv21(x))) via MFMA -> bf16 padded layout.
//     blocks 784..847: halo-zero (overlapped).
__global__ __launch_bounds__(256, 2) void k1_mfma(const float* __restrict__ x,
                                                  const float* __restrict__ w21,
                                                  const float* __restrict__ g,
                                                  const float* __restrict__ bb,
                                                  unsigned short* __restrict__ y) {
    const int blk = blockIdx.x;
    const int tid = threadIdx.x;
    if (blk >= 784) { halo_zero(blk - 784, tid, y); return; }

    __shared__ unsigned short Alds[64][264];     // 64 o x (256 c + 8 pad) = 33 KB
    __shared__ unsigned short Blds[4][64][40];   // per-wave 64 px x (32 c + 8 pad) = 20 KB

    const int lane = tid & 63;
    const int wv   = tid >> 6;
    const int gq   = blk / 49;
    const int s    = blk - gq * 49;
    const int p0   = s * 64;
    const int nt   = __builtin_amdgcn_readfirstlane(gq * 4 + wv);

    {   // stage A: convert fp32 weights in-block (w is L2/L3-hot across blocks)
        const int o  = tid >> 2;
        const int cb = (tid & 3) * 64;
        const float* wp = w21 + o * C + cb;
        unsigned short* ap = &Alds[o][cb];
#pragma unroll
        for (int j = 0; j < 8; ++j) {
            f32x4 lo = *(const f32x4*)(wp + j * 8);
            f32x4 hi = *(const f32x4*)(wp + j * 8 + 4);
            union { unsigned d[4]; short8 v; } pk;
            pk.d[0] = pack2(lo.x, lo.y); pk.d[1] = pack2(lo.z, lo.w);
            pk.d[2] = pack2(hi.x, hi.y); pk.d[3] = pack2(hi.z, hi.w);
            *(short8*)(ap + j * 8) = pk.v;
        }
    }
    __syncthreads();   // the only barrier

    const float* xw = x + (size_t)nt * (C * HW) + p0 + lane;
    unsigned short (*Bw)[40] = Blds[wv];

    f32x4 acc[4][4];
#pragma unroll
    for (int nb = 0; nb < 4; ++nb)
#pragma unroll
        for (int mb = 0; mb < 4; ++mb) acc[nb][mb] = (f32x4)0.0f;

    const int frow = lane & 15;
    const int fk8  = (lane >> 4) * 8;

    float buf[2][32];
#pragma unroll
    for (int j = 0; j < 32; ++j) buf[0][j] = xw[(size_t)j * HW];

#pragma unroll
    for (int ks = 0; ks < 8; ++ks) {
        const int cur = ks & 1;
        if (ks < 7) {
            const float* xn = xw + (size_t)((ks + 1) * 32) * HW;
#pragma unroll
            for (int j = 0; j < 32; ++j) buf[cur ^ 1][j] = xn[(size_t)j * HW];
        }
#pragma unroll
        for (int q = 0; q < 4; ++q) {
            union { unsigned d[4]; short8 v; } pk;
#pragma unroll
            for (int jj = 0; jj < 4; ++jj)
                pk.d[jj] = pack2(buf[cur][q * 8 + 2 * jj], buf[cur][q * 8 + 2 * jj + 1]);
            *(short8*)&Bw[lane][q * 8] = pk.v;
        }
        short8 bfrag[4], afrag[4];
#pragma unroll
        for (int nb = 0; nb < 4; ++nb)
            bfrag[nb] = *(const short8*)&Bw[nb * 16 + frow][fk8];
#pragma unroll
        for (int mb = 0; mb < 4; ++mb)
            afrag[mb] = *(const short8*)&Alds[mb * 16 + frow][ks * 32 + fk8];
#pragma unroll
        for (int nb = 0; nb < 4; ++nb)
#pragma unroll
            for (int mb = 0; mb < 4; ++mb)
                acc[nb][mb] = __builtin_amdgcn_mfma_f32_16x16x32_bf16(
                    afrag[mb], bfrag[nb], acc[nb][mb], 0, 0, 0);
    }

    // epilogue: D col = lane&15 (pixel), row = (lane>>4)*4 + r (output o); bf16 store
    unsigned short* ybase = y + (size_t)nt * CR * YPLANE;
    const int rbase = (lane >> 4) * 4;
#pragma unroll
    for (int nb = 0; nb < 4; ++nb) {
        const int p = p0 + nb * 16 + frow;
        const int r = p / WIDTH;
        const int c = p - r * WIDTH;
        const int pidx = (r + 1) * PW + (c + 1);
#pragma unroll
        for (int mb = 0; mb < 4; ++mb)
#pragma unroll
            for (int rr = 0; rr < 4; ++rr) {
                int o = mb * 16 + rbase + rr;
                float v = relu(fmaf(acc[nb][mb][rr], g[o] * BN_INV, bb[o]));
                ybase[(size_t)o * YPLANE + pidx] = f2bf(v);
            }
    }
}

// k2f: fused corr + bn22 + relu + conv22 + bn23 + residual + relu.
// thread = (task, h); task = (nt, row, 4-col group); h = ch-octet.
// o-mapping h-interleaved: this thread handles o = oi*8 + h, oi = 0..31.
// acc[9][4] keeps VGPR ~90 (no launch_bounds cap -> no spill).
__global__ __launch_bounds__(256) void k2_fused(const unsigned short* __restrict__ y,
                                                const float* __restrict__ g22,
                                                const float* __restrict__ b22,
                                                const float* __restrict__ w2,
                                                const float* __restrict__ g23,
                                                const float* __restrict__ b23,
                                                const float* __restrict__ x,
                                                float* __restrict__ out) {
    __shared__ float w2s[256][12];   // [o][k]: w2*g23*BN_INV (k<9), [9]=b23, 48B rows
    {
        const int o = threadIdx.x;
        const float sc = g23[o] * BN_INV;
#pragma unroll
        for (int k = 0; k < 9; ++k) w2s[o][k] = w2[o * 9 + k] * sc;
        w2s[o][9] = b23[o];
        w2s[o][10] = 0.0f; w2s[o][11] = 0.0f;
    }
    __syncthreads();

    const int gt   = blockIdx.x * 256 + threadIdx.x;   // 0..401407
    const int h    = gt & 7;                           // ch octet
    const int task = gt >> 3;                          // 0..50175
    const int nt   = task / 784;                       // 784 = 56 rows * 14 col4-groups
    const int rm   = task - nt * 784;
    const int r    = rm / 14;
    const int cg   = rm - r * 14;
    const int c0   = cg * 4;
    const int nt2  = ((nt & (TT - 1)) < TT - 1) ? nt + 1 : nt;

    // dword pointers into the padded bf16 planes (8B-aligned rows)
    const unsigned* y1 = (const unsigned*)(y + ((size_t)nt * CR + h * 8) * YPLANE
                                             + (size_t)(r + 1) * PW + c0);
    const unsigned* y2 = (const unsigned*)(y + ((size_t)nt2 * CR + h * 8) * YPLANE
                                             + (size_t)r * PW + c0);

    float acc[9][4];
#pragma unroll
    for (int k = 0; k < 9; ++k)
#pragma unroll
        for (int px = 0; px < 4; ++px) acc[k][px] = 0.0f;

#pragma unroll
    for (int ch = 0; ch < 8; ++ch) {
        const unsigned* p1 = y1 + ch * (YPLANE / 2);
        unsigned u0 = p1[0], u1 = p1[1], u2 = p1[2];
        float a[4] = { bfHI(u0), bfLO(u1), bfHI(u1), bfLO(u2) };

        const unsigned* p2 = y2 + ch * (YPLANE / 2);
#pragma unroll
        for (int dy = 0; dy < 3; ++dy) {
            const unsigned* pr = p2 + dy * (PW / 2);
            unsigned v0 = pr[0], v1 = pr[1], v2 = pr[2];
            float w[6] = { bfLO(v0), bfHI(v0), bfLO(v1), bfHI(v1), bfLO(v2), bfHI(v2) };
#pragma unroll
            for (int dx = 0; dx < 3; ++dx) {
                int k = dy * 3 + dx;
#pragma unroll
                for (int px = 0; px < 4; ++px)
                    acc[k][px] = fmaf(a[px], w[px + dx], acc[k][px]);
            }
        }
    }

    // reduce over the 8 ch-octet lanes; all lanes end with the full sum
#pragma unroll
    for (int k = 0; k < 9; ++k)
#pragma unroll
        for (int px = 0; px < 4; ++px) {
            float v = acc[k][px];
            v += __shfl_xor(v, 1);
            v += __shfl_xor(v, 2);
            v += __shfl_xor(v, 4);
            acc[k][px] = v;
        }

    // bn22 + relu in-register (scale folds the 1/CR)
#pragma unroll
    for (int k = 0; k < 9; ++k) {
        float sck = g22[k] * (BN_INV / (float)CR);
        float bvk = b22[k];
#pragma unroll
        for (int px = 0; px < 4; ++px)
            acc[k][px] = relu(fmaf(acc[k][px], sck, bvk));
    }

    // conv22 + bn23 + residual + relu: o = oi*8 + h
    const int pxl = rm * 4;
    const float* xb = x   + (size_t)nt * (C * HW) + pxl;
    float*       ob = out + (size_t)nt * (C * HW) + pxl;

#pragma unroll 4
    for (int oi = 0; oi < 32; ++oi) {
        const int o = oi * 8 + h;
        f32x4 wk0 = *(const f32x4*)&w2s[o][0];
        f32x4 wk1 = *(const f32x4*)&w2s[o][4];
        f32x4 wk2 = *(const f32x4*)&w2s[o][8];   // .x = w8, .y = b23
        f32x4 xr  = *(const f32x4*)(xb + (size_t)o * HW);
        f32x4 ov;
#pragma unroll
        for (int px = 0; px < 4; ++px) {
            float sx = wk2.y;                     // b23
            sx = fmaf(wk0.x, acc[0][px], sx);
            sx = fmaf(wk0.y, acc[1][px], sx);
            sx = fmaf(wk0.z, acc[2][px], sx);
            sx = fmaf(wk0.w, acc[3][px], sx);
            sx = fmaf(wk1.x, acc[4][px], sx);
            sx = fmaf(wk1.y, acc[5][px], sx);
            sx = fmaf(wk1.z, acc[6][px], sx);
            sx = fmaf(wk1.w, acc[7][px], sx);
            sx = fmaf(wk2.x, acc[8][px], sx);
            ov[px] = relu(sx + xr[px]);
        }
        *(f32x4*)(ob + (size_t)o * HW) = ov;
    }
}

extern "C" void kernel_launch(void* const* d_in, const int* in_sizes, int n_in,
                              void* d_out, int out_size, void* d_ws, size_t ws_size,
                              hipStream_t stream) {
    const float* x   = (const float*)d_in[0];
    const float* w21 = (const float*)d_in[1];
    const float* g21 = (const float*)d_in[2];
    const float* b21 = (const float*)d_in[3];
    const float* g22 = (const float*)d_in[4];
    const float* b22 = (const float*)d_in[5];
    const float* w22 = (const float*)d_in[6];
    const float* g23 = (const float*)d_in[7];
    const float* b23 = (const float*)d_in[8];
    float* out = (float*)d_out;

    // y: bf16 padded [64][64][58][64] = 30.4MB in d_ws
    unsigned short* yb = (unsigned short*)d_ws;
    k1_mfma <<<848,  256, 0, stream>>>(x, w21, g21, b21, yb);
    k2_fused<<<1568, 256, 0, stream>>>(yb, g22, b22, w22, g23, b23, x, out);
}